// Round 11
// baseline (164.399 us; speedup 1.0000x reference)
//
#include <hip/hip_runtime.h>

// MultiHeadAttention: B=1, S=4096, D=768, H=12, HD=64, causal, fp32 in/out.
// Round 22: GEMM double-buffer. Attn is byte-identical to R21 (control:
// ~48.9us, conflicts 1.585M). The non-attn kernels total ~100us; both GEMMs
// used the m97-style 2-barrier loop whose per-K-step vmcnt(0) drain exposes
// full staging latency (12 K-steps only, 2-3 blocks/CU). This round applies
// the R13-verified schedule to mfma_gemm_kernel:
//   prologue: stage tile0 -> buf0
//   per K-step k: lgkmcnt(0); s_barrier   (reads of tile k-1 retired)
//                 stage tile k+1 -> buf[(k+1)&1]   (7/5 DMA, rides through)
//                 vmcnt(7|5) [last: 0]; s_barrier  (tile k landed)
//                 compute from buf[k&1]
// LDS: MODE0 2x28=56KB (2 blocks/CU, grid 768 -> 1.5 rounds - accepted),
// MODE1 2x20=40KB (grid-limited 2/CU). Epilogues unchanged. Prep unchanged.

typedef short bf16x8 __attribute__((ext_vector_type(8)));
typedef float f32x4 __attribute__((ext_vector_type(4)));
typedef unsigned short u16;

static constexpr int S_LEN = 4096;
static constexpr int DIM   = 768;
static constexpr int NH    = 12;
// softmax scale folded into Q projection: 1/sqrt(64) * log2(e)
static constexpr float QSCALE = 0.125f * 1.44269504088896340736f;

__device__ inline u16 f2bf(float f) {
  union { float f; unsigned int u; } v; v.f = f;
  unsigned int r = v.u + 0x7FFFu + ((v.u >> 16) & 1u);  // RNE
  return (u16)(r >> 16);
}

__device__ inline void gload_lds16(const u16* g, u16* s) {
  __builtin_amdgcn_global_load_lds(
      (const __attribute__((address_space(1))) unsigned int*)g,
      (__attribute__((address_space(3))) unsigned int*)s, 16, 0, 0);
}

// P-pack helpers: exp2 4+4 scores, accumulate row-sum, cvt_pk to bf16,
// quad-transpose via permlane32/16 swaps. All scalar args -> no scratch.
__device__ inline bf16x8 packP(f32x4 sA, f32x4 sB, float& ls) {
  const float p0 = __builtin_amdgcn_exp2f(sA[0]);
  const float p1 = __builtin_amdgcn_exp2f(sA[1]);
  const float p2 = __builtin_amdgcn_exp2f(sA[2]);
  const float p3 = __builtin_amdgcn_exp2f(sA[3]);
  const float r0 = __builtin_amdgcn_exp2f(sB[0]);
  const float r1 = __builtin_amdgcn_exp2f(sB[1]);
  const float r2 = __builtin_amdgcn_exp2f(sB[2]);
  const float r3 = __builtin_amdgcn_exp2f(sB[3]);
  ls += (p0 + p1 + p2 + p3) + (r0 + r1 + r2 + r3);
  unsigned a0, a1, b0, b1;
  asm("v_cvt_pk_bf16_f32 %0, %1, %2" : "=v"(a0) : "v"(p0), "v"(p1));
  asm("v_cvt_pk_bf16_f32 %0, %1, %2" : "=v"(a1) : "v"(p2), "v"(p3));
  asm("v_cvt_pk_bf16_f32 %0, %1, %2" : "=v"(b0) : "v"(r0), "v"(r1));
  asm("v_cvt_pk_bf16_f32 %0, %1, %2" : "=v"(b1) : "v"(r2), "v"(r3));
  asm("v_permlane32_swap_b32 %0, %1" : "+v"(a0), "+v"(b0));
  asm("v_permlane16_swap_b32 %0, %1" : "+v"(a0), "+v"(b0));
  asm("v_permlane32_swap_b32 %0, %1" : "+v"(a1), "+v"(b1));
  asm("v_permlane16_swap_b32 %0, %1" : "+v"(a1), "+v"(b1));
  union { unsigned u[4]; bf16x8 v; } U;
  U.u[0] = a0; U.u[1] = a1; U.u[2] = b0; U.u[3] = b1;
  return U.v;
}

__device__ inline bf16x8 packPmask(f32x4 sA, f32x4 sB, float& ls,
                                   int kvb, int quad, int qg) {
  // kv index of element r in sA: kvb + quad*4 + r ; in sB: +16.
  float p0 = __builtin_amdgcn_exp2f(sA[0]);
  float p1 = __builtin_amdgcn_exp2f(sA[1]);
  float p2 = __builtin_amdgcn_exp2f(sA[2]);
  float p3 = __builtin_amdgcn_exp2f(sA[3]);
  float r0 = __builtin_amdgcn_exp2f(sB[0]);
  float r1 = __builtin_amdgcn_exp2f(sB[1]);
  float r2 = __builtin_amdgcn_exp2f(sB[2]);
  float r3 = __builtin_amdgcn_exp2f(sB[3]);
  const int k0 = kvb + quad * 4;
  if (k0 + 0 > qg)  p0 = 0.f;
  if (k0 + 1 > qg)  p1 = 0.f;
  if (k0 + 2 > qg)  p2 = 0.f;
  if (k0 + 3 > qg)  p3 = 0.f;
  if (k0 + 16 > qg) r0 = 0.f;
  if (k0 + 17 > qg) r1 = 0.f;
  if (k0 + 18 > qg) r2 = 0.f;
  if (k0 + 19 > qg) r3 = 0.f;
  ls += (p0 + p1 + p2 + p3) + (r0 + r1 + r2 + r3);
  unsigned a0, a1, b0, b1;
  asm("v_cvt_pk_bf16_f32 %0, %1, %2" : "=v"(a0) : "v"(p0), "v"(p1));
  asm("v_cvt_pk_bf16_f32 %0, %1, %2" : "=v"(a1) : "v"(p2), "v"(p3));
  asm("v_cvt_pk_bf16_f32 %0, %1, %2" : "=v"(b0) : "v"(r0), "v"(r1));
  asm("v_cvt_pk_bf16_f32 %0, %1, %2" : "=v"(b1) : "v"(r2), "v"(r3));
  asm("v_permlane32_swap_b32 %0, %1" : "+v"(a0), "+v"(b0));
  asm("v_permlane16_swap_b32 %0, %1" : "+v"(a0), "+v"(b0));
  asm("v_permlane32_swap_b32 %0, %1" : "+v"(a1), "+v"(b1));
  asm("v_permlane16_swap_b32 %0, %1" : "+v"(a1), "+v"(b1));
  union { unsigned u[4]; bf16x8 v; } U;
  U.u[0] = a0; U.u[1] = a1; U.u[2] = b0; U.u[3] = b1;
  return U.v;
}

// ---------------------------------------------------------------------------
// Prep: z<4 -> transpose W[z] fp32 -> bf16 W^T; z==4 -> convert x -> bf16.
__global__ __launch_bounds__(256)
void prep_kernel(const float* __restrict__ x, const float* __restrict__ w0,
                 const float* __restrict__ w1, const float* __restrict__ w2,
                 const float* __restrict__ w3, u16* __restrict__ xb,
                 u16* __restrict__ t0, u16* __restrict__ t1,
                 u16* __restrict__ t2, u16* __restrict__ t3) {
  if (blockIdx.z == 4) {
    const size_t n = (size_t)S_LEN * DIM;
    const int id = blockIdx.y * 12 + blockIdx.x;
    const size_t stride = (size_t)144 * 256 * 8;
    for (size_t i = ((size_t)id * 256 + threadIdx.x) * 8; i < n; i += stride) {
      const float4 a = *(const float4*)(x + i);
      const float4 b = *(const float4*)(x + i + 4);
      bf16x8 o;
      o[0] = (short)f2bf(a.x); o[1] = (short)f2bf(a.y);
      o[2] = (short)f2bf(a.z); o[3] = (short)f2bf(a.w);
      o[4] = (short)f2bf(b.x); o[5] = (short)f2bf(b.y);
      o[6] = (short)f2bf(b.z); o[7] = (short)f2bf(b.w);
      *(bf16x8*)(xb + i) = o;
    }
    return;
  }
  __shared__ float T[64][65];
  const float* src; u16* dst;
  switch (blockIdx.z) {
    case 0: src = w0; dst = t0; break;
    case 1: src = w1; dst = t1; break;
    case 2: src = w2; dst = t2; break;
    default: src = w3; dst = t3; break;
  }
  const int k0 = blockIdx.y * 64, n0 = blockIdx.x * 64;
  const int r = threadIdx.x >> 2, c0 = (threadIdx.x & 3) * 16;
#pragma unroll
  for (int i = 0; i < 4; ++i) {
    const float4 v = *(const float4*)(src + (size_t)(k0 + r) * DIM + n0 + c0 + i * 4);
    T[r][c0 + i * 4 + 0] = v.x;
    T[r][c0 + i * 4 + 1] = v.y;
    T[r][c0 + i * 4 + 2] = v.z;
    T[r][c0 + i * 4 + 3] = v.w;
  }
  __syncthreads();
  bf16x8 o0, o1;
#pragma unroll
  for (int i = 0; i < 8; ++i) {
    o0[i] = (short)f2bf(T[c0 + i][r]);
    o1[i] = (short)f2bf(T[c0 + 8 + i][r]);
  }
  *(bf16x8*)(dst + (size_t)(n0 + r) * DIM + k0 + c0) = o0;
  *(bf16x8*)(dst + (size_t)(n0 + r) * DIM + k0 + c0 + 8) = o1;
}

// ---------------------------------------------------------------------------
// MFMA GEMM, BK=64, BN=96, DOUBLE-BUFFERED global_load_lds staging with XOR
// chunk swizzle + counted vmcnt (R13 schedule; see file header).
// MODE 0: fused QKV (BM=128, grid 24x32). wi = n0/768: Q (scaled), K
//         row-major bf16 via SWAPPED mfma (C^T frag -> packed 8B stores);
//         V -> VT[768][4096] via normal orientation (already packed).
// MODE 1: out GEMM (BM=64, grid 8x64), fp32 + bias, swapped -> float4 stores.
template <int MODE>
__global__ __launch_bounds__(256)
void mfma_gemm_kernel(const u16* __restrict__ A, const u16* __restrict__ Bq,
                      const u16* __restrict__ Bk, const u16* __restrict__ Bv,
                      const float* __restrict__ bias, u16* __restrict__ Qb,
                      u16* __restrict__ Kb, u16* __restrict__ VT,
                      float* __restrict__ Out) {
  constexpr int MT  = (MODE == 0) ? 4 : 2;   // m-frags (16) per wave
  constexpr int BM  = MT * 32;
  constexpr int ASZ = BM * 64;               // u16 per A tile
  constexpr int BSZ = 96 * 64;               // u16 per B tile
  __shared__ __align__(16) u16 Al[2 * ASZ];
  __shared__ __align__(16) u16 Bl[2 * BSZ];

  const int tid  = threadIdx.x;
  const int wv   = tid >> 6;
  const int lane = tid & 63;
  const int quad = lane >> 4;
  const int l16  = lane & 15;
  const int wr = wv >> 1, wc = wv & 1;
  const int m0 = blockIdx.y * BM;
  const int n0 = blockIdx.x * 96;

  int wi = 0, nb = n0;
  const u16* BT = Bq;
  if (MODE == 0) {
    wi = n0 / DIM;
    nb = n0 - wi * DIM;
    BT = (wi == 0) ? Bq : (wi == 1) ? Bk : Bv;
  }

  const int sr8 = lane >> 3;              // row within 8-row staging slab
  const int sc  = ((lane & 7) ^ sr8) * 8; // swizzled source chunk (u16)
  const int key = l16 & 7;                // read-side swizzle key

  const bool swp = (MODE == 1) || (wi < 2);  // uniform per block

  f32x4 acc[MT][3] = {};

  constexpr int NK = DIM / 64;            // 12 K-steps

  // Prologue: stage tile 0 into buffer 0 (7/5 DMA per wave).
#pragma unroll
  for (int j = 0; j < MT; ++j)
    gload_lds16(A + (size_t)(m0 + wv * (BM / 4) + j * 8 + sr8) * DIM + sc,
                &Al[(wv * (BM / 4) + j * 8) * 64]);
#pragma unroll
  for (int j = 0; j < 3; ++j)
    gload_lds16(BT + (size_t)(nb + wv * 24 + j * 8 + sr8) * DIM + sc,
                &Bl[(wv * 24 + j * 8) * 64]);

  for (int k = 0; k < NK; ++k) {
    // Barrier A: all ds_reads of tile k-1 retired -> its buffer reusable.
    asm volatile("s_waitcnt lgkmcnt(0)" ::: "memory");
    __builtin_amdgcn_s_barrier();

    const int cur = k & 1;
    if (k + 1 < NK) {
      const int nxt = (k + 1) & 1;
      const int k0n = (k + 1) * 64;
#pragma unroll
      for (int j = 0; j < MT; ++j)
        gload_lds16(A + (size_t)(m0 + wv * (BM / 4) + j * 8 + sr8) * DIM + k0n + sc,
                    &Al[nxt * ASZ + (wv * (BM / 4) + j * 8) * 64]);
#pragma unroll
      for (int j = 0; j < 3; ++j)
        gload_lds16(BT + (size_t)(nb + wv * 24 + j * 8 + sr8) * DIM + k0n + sc,
                    &Bl[nxt * BSZ + (wv * 24 + j * 8) * 64]);
      // Tile k's loads (issued last iter) retired; k+1's ride through.
      if (MODE == 0) asm volatile("s_waitcnt vmcnt(7)" ::: "memory");
      else           asm volatile("s_waitcnt vmcnt(5)" ::: "memory");
    } else {
      asm volatile("s_waitcnt vmcnt(0)" ::: "memory");
    }
    __builtin_amdgcn_s_barrier();

#pragma unroll
    for (int kh = 0; kh < 2; ++kh) {
      const int cb = kh * 4;
      bf16x8 af[MT], bfr[3];
#pragma unroll
      for (int mt = 0; mt < MT; ++mt) {
        const int row = wr * (BM / 2) + mt * 16 + l16;
        af[mt] = *(const bf16x8*)&Al[cur * ASZ + row * 64 + ((cb + quad) ^ key) * 8];
      }
#pragma unroll
      for (int nt = 0; nt < 3; ++nt) {
        const int row = wc * 48 + nt * 16 + l16;
        bfr[nt] = *(const bf16x8*)&Bl[cur * BSZ + row * 64 + ((cb + quad) ^ key) * 8];
      }
      if (swp) {
        // C^T: D = Bfrag x Afrag -> lane holds row m=l16, cols n=quad*4+r.
#pragma unroll
        for (int mt = 0; mt < MT; ++mt)
#pragma unroll
          for (int nt = 0; nt < 3; ++nt)
            acc[mt][nt] = __builtin_amdgcn_mfma_f32_16x16x32_bf16(
                bfr[nt], af[mt], acc[mt][nt], 0, 0, 0);
      } else {
#pragma unroll
        for (int mt = 0; mt < MT; ++mt)
#pragma unroll
          for (int nt = 0; nt < 3; ++nt)
            acc[mt][nt] = __builtin_amdgcn_mfma_f32_16x16x32_bf16(
                af[mt], bfr[nt], acc[mt][nt], 0, 0, 0);
      }
    }
  }

  if (MODE == 0 && wi >= 2) {
    // V path (normal orientation): lane holds col=l16, rows quad*4+r.
#pragma unroll
    for (int mt = 0; mt < MT; ++mt) {
#pragma unroll
      for (int nt = 0; nt < 3; ++nt) {
        const int row  = m0 + wr * (BM / 2) + mt * 16 + quad * 4;
        const int ncol = nb + wc * 48 + nt * 16 + l16;
        u16 pk[4];
#pragma unroll
        for (int r = 0; r < 4; ++r) pk[r] = f2bf(acc[mt][nt][r]);
        unsigned long long v;
        __builtin_memcpy(&v, pk, 8);
        *(unsigned long long*)(VT + (size_t)ncol * S_LEN + row) = v;
      }
    }
  } else if (MODE == 0) {
    // Q/K path (swapped): packed 8B row-major stores.
    u16* dst = (wi == 0) ? Qb : Kb;
    const float sc_out = (wi == 0) ? QSCALE : 1.0f;
#pragma unroll
    for (int mt = 0; mt < MT; ++mt) {
#pragma unroll
      for (int nt = 0; nt < 3; ++nt) {
        const int row = m0 + wr * (BM / 2) + mt * 16 + l16;
        const int ncb = nb + wc * 48 + nt * 16 + quad * 4;
        u16 pk[4];
#pragma unroll
        for (int r = 0; r < 4; ++r) pk[r] = f2bf(acc[mt][nt][r] * sc_out);
        unsigned long long v;
        __builtin_memcpy(&v, pk, 8);
        *(unsigned long long*)(dst + (size_t)row * DIM + ncb) = v;
      }
    }
  } else {
    // Out GEMM (swapped): float4 stores + float4 bias loads.
#pragma unroll
    for (int mt = 0; mt < MT; ++mt) {
#pragma unroll
      for (int nt = 0; nt < 3; ++nt) {
        const int row = m0 + wr * (BM / 2) + mt * 16 + l16;
        const int ncb = n0 + wc * 48 + nt * 16 + quad * 4;
        const float4 b4 = *(const float4*)(bias + ncb);
        float4 ov;
        ov.x = acc[mt][nt][0] + b4.x;
        ov.y = acc[mt][nt][1] + b4.y;
        ov.z = acc[mt][nt][2] + b4.z;
        ov.w = acc[mt][nt][3] + b4.w;
        *(float4*)(Out + (size_t)row * DIM + ncb) = ov;
      }
    }
  }
}

// ---------------------------------------------------------------------------
// Flash causal attention. 1536 blocks x 256 thr, one 32-row q-tile each.
// Wave w = DISJOINT 32-wide kv-quarter; covers all 32 q-rows (2 q-sets).
// Per phase per wave: 4 K + 4 V ds_read_b128, zero duplication (LDS traffic
// halved vs R16 - conflict counter verified in R20). Fixed-max softmax;
// in-register P (swapped QK^T + cvt_pk + permlane). Epilogue: publish-once
// gather-sum per q-set (waves 0/1 finalize). 32KB LDS; 4 blocks/CU VGPR cap.
// BYTE-IDENTICAL to R21 (control for this round's GEMM change).
__global__ __launch_bounds__(256, 4)
void attn_mfma_kernel(const u16* __restrict__ Qb, const u16* __restrict__ Kb,
                      const u16* __restrict__ VTb, u16* __restrict__ ctx) {
  // Kl (128x64) + Vl (64x128) = 16384 u16 = 32 KB exact. Obuf reuses front.
  __shared__ __align__(16) u16 KVl[128 * 64 + 64 * 128];
  u16* const Kl = KVl;                   // [kv][d] swizzled
  u16* const Vl = KVl + 128 * 64;        // [d][kv] swizzled

  const int tid  = threadIdx.x;
  const int w    = tid >> 6;             // kv-quarter index
  const int lane = tid & 63;
  const int quad = lane >> 4;
  const int l16  = lane & 15;
  const int key  = l16 & 7;

  // Mapping: big tiles dispatch first (LPT); h = id%12 keeps per-XCD head
  // set = {x, x+4, x+8} mod 12 (3 heads x ~2MB K+V, L2-resident per XCD).
  const int id = blockIdx.x;
  const int to = id / 12;
  const int h  = id - to * 12;
  const int qt = 127 - to;
  const int q0 = qt * 32;

  const int sr8  = lane >> 3;               // K: row-in-slab
  const int scK  = ((lane & 7) ^ sr8) * 8;  // K: swizzled source col
  const int sr16 = lane >> 4;               // V: row-in-slab

  // Q fragments: 2 q-sets x 2 d-halves, named scalars (Qb is L2-hot).
  bf16x8 aq00, aq01, aq10, aq11;
  {
    const u16* qp0 = Qb + (size_t)(q0 + l16) * DIM + h * 64 + quad * 8;
    aq00 = *(const bf16x8*)(qp0);
    aq01 = *(const bf16x8*)(qp0 + 32);
    const u16* qp1 = Qb + (size_t)(q0 + 16 + l16) * DIM + h * 64 + quad * 8;
    aq10 = *(const bf16x8*)(qp1);
    aq11 = *(const bf16x8*)(qp1 + 32);
  }

  f32x4 o00 = {}, o01 = {}, o02 = {}, o03 = {};
  f32x4 o10 = {}, o11 = {}, o12 = {}, o13 = {};
  float ls0 = 0.f, ls1 = 0.f;
  const int qg0 = q0 + l16;        // lane-fixed q rows (swapped layout)
  const int qg1 = q0 + 16 + l16;

  const int niter = qt / 4 + 1;    // 128-wide slabs

#pragma unroll 1
  for (int i = 0; i < niter; ++i) {
    const int k0g = i * 128;
    // Barrier A: all LDS reads of slab i-1 retired before Kl/Vl overwrite.
    asm volatile("s_waitcnt lgkmcnt(0)" ::: "memory");
    __builtin_amdgcn_s_barrier();

    // Stage K(i) then V(i) (issue order matters for counted vmcnt).
#pragma unroll
    for (int jj = 0; jj < 4; ++jj)
      gload_lds16(Kb + (size_t)(k0g + w * 32 + jj * 8 + sr8) * DIM + h * 64 + scK,
                  &Kl[(w * 32 + jj * 8) * 64]);
#pragma unroll
    for (int jj = 0; jj < 4; ++jj) {
      const int vrow = w * 16 + jj * 4 + sr16;
      const int vcol = (l16 ^ (vrow & 7)) * 8;
      gload_lds16(VTb + (size_t)(h * 64 + vrow) * S_LEN + k0g + vcol,
                  &Vl[(w * 16 + jj * 4) * 128]);
    }
    // Barrier B: K(i) landed (V(i)'s 4 loads stay in flight).
    asm volatile("s_waitcnt vmcnt(4)" ::: "memory");
    __builtin_amdgcn_s_barrier();

    const int g = 4 * i + w;             // this wave's kv-quarter (32-wide)
    const bool act = g <= qt;
    bf16x8 pa0v, pa1v;
    if (act) {
      __builtin_amdgcn_s_setprio(1);
      // K fragments once (shared by both q-sets): 4 x ds_read_b128.
      const int rA = (w * 32 + l16) * 64;
      const int rB = (w * 32 + 16 + l16) * 64;
      const bf16x8 bk00 = *(const bf16x8*)&Kl[rA + (quad ^ key) * 8];
      const bf16x8 bk01 = *(const bf16x8*)&Kl[rA + ((quad ^ 4) ^ key) * 8];
      const bf16x8 bk10 = *(const bf16x8*)&Kl[rB + (quad ^ key) * 8];
      const bf16x8 bk11 = *(const bf16x8*)&Kl[rB + ((quad ^ 4) ^ key) * 8];
      const f32x4 Z = {0.f, 0.f, 0.f, 0.f};
      // S^T = K Q^T (swapped): lane holds q=l16, kv=32w+16t+4*quad+r.
      f32x4 sA = __builtin_amdgcn_mfma_f32_16x16x32_bf16(bk00, aq00, Z, 0, 0, 0);
      sA = __builtin_amdgcn_mfma_f32_16x16x32_bf16(bk01, aq01, sA, 0, 0, 0);
      f32x4 sB = __builtin_amdgcn_mfma_f32_16x16x32_bf16(bk10, aq00, Z, 0, 0, 0);
      sB = __builtin_amdgcn_mfma_f32_16x16x32_bf16(bk11, aq01, sB, 0, 0, 0);
      f32x4 sC = __builtin_amdgcn_mfma_f32_16x16x32_bf16(bk00, aq10, Z, 0, 0, 0);
      sC = __builtin_amdgcn_mfma_f32_16x16x32_bf16(bk01, aq11, sC, 0, 0, 0);
      f32x4 sD = __builtin_amdgcn_mfma_f32_16x16x32_bf16(bk10, aq10, Z, 0, 0, 0);
      sD = __builtin_amdgcn_mfma_f32_16x16x32_bf16(bk11, aq11, sD, 0, 0, 0);

      if (g == qt) {
        const int kvb = k0g + w * 32;
        pa0v = packPmask(sA, sB, ls0, kvb, quad, qg0);
        pa1v = packPmask(sC, sD, ls1, kvb, quad, qg1);
      } else {
        pa0v = packP(sA, sB, ls0);
        pa1v = packP(sC, sD, ls1);
      }
    }

    // Barrier C (ALL waves): V(i) landed for every wave's quarter.
    asm volatile("s_waitcnt vmcnt(0)" ::: "memory");
    __builtin_amdgcn_s_barrier();

    if (act) {
      // O += P V : 4 V reads (b128), each feeds BOTH q-sets' MFMAs.
      const int cc = ((w * 4 + quad) ^ key) * 8;
      const bf16x8 vb0 = *(const bf16x8*)&Vl[(l16) * 128 + cc];
      o00 = __builtin_amdgcn_mfma_f32_16x16x32_bf16(pa0v, vb0, o00, 0, 0, 0);
      o10 = __builtin_amdgcn_mfma_f32_16x16x32_bf16(pa1v, vb0, o10, 0, 0, 0);
      const bf16x8 vb1 = *(const bf16x8*)&Vl[(16 + l16) * 128 + cc];
      o01 = __builtin_amdgcn_mfma_f32_16x16x32_bf16(pa0v, vb1, o01, 0, 0, 0);
      o11 = __builtin_amdgcn_mfma_f32_16x16x32_bf16(pa1v, vb1, o11, 0, 0, 0);
      const bf16x8 vb2 = *(const bf16x8*)&Vl[(32 + l16) * 128 + cc];
      o02 = __builtin_amdgcn_mfma_f32_16x16x32_bf16(pa0v, vb2, o02, 0, 0, 0);
      o12 = __builtin_amdgcn_mfma_f32_16x16x32_bf16(pa1v, vb2, o12, 0, 0, 0);
      const bf16x8 vb3 = *(const bf16x8*)&Vl[(48 + l16) * 128 + cc];
      o03 = __builtin_amdgcn_mfma_f32_16x16x32_bf16(pa0v, vb3, o03, 0, 0, 0);
      o13 = __builtin_amdgcn_mfma_f32_16x16x32_bf16(pa1v, vb3, o13, 0, 0, 0);
      __builtin_amdgcn_s_setprio(0);
    }
  }

  // Epilogue: gather-sum the 4 kv-quarter partials per q-set.
  // Obuf lane stride 20 floats (conflict-free); lbuf at +5120.
  __syncthreads();  // all waves done with Kl/Vl reads before Obuf reuse
  float* Obuf  = (float*)KVl;  // 256 lanes x 20 floats = 20 KB
  float* lbufF = Obuf + 5120;  // 256 floats = 1 KB
  const int bme = (w * 64 + lane) * 20;

  // --- set 0: publish, wave 0 gathers.
  *(f32x4*)&Obuf[bme + 0]  = o00;
  *(f32x4*)&Obuf[bme + 4]  = o01;
  *(f32x4*)&Obuf[bme + 8]  = o02;
  *(f32x4*)&Obuf[bme + 12] = o03;
  lbufF[w * 64 + lane] = ls0;
  __syncthreads();
  if (w == 0) {
#pragma unroll
    for (int wq = 1; wq < 4; ++wq) {
      const int bp = (wq * 64 + lane) * 20;
      o00 += *(const f32x4*)&Obuf[bp + 0];
      o01 += *(const f32x4*)&Obuf[bp + 4];
      o02 += *(const f32x4*)&Obuf[bp + 8];
      o03 += *(const f32x4*)&Obuf[bp + 12];
      ls0 += lbufF[wq * 64 + lane];
    }
  }
  __syncthreads();

  // --- set 1: publish, wave 1 gathers.
  *(f32x4*)&Obuf[bme + 0]  = o10;
  *(f32x4*)&Obuf[bme + 4]  = o11;
  *(f32x4*)&Obuf[bme + 8]  = o12;
  *(f32x4*)&Obuf[bme + 12] = o13;
  lbufF[w * 64 + lane] = ls1;
  __syncthreads();
  if (w == 1) {
#pragma unroll
    for (int wq = 0; wq < 4; ++wq) {
      if (wq == 1) continue;
      const int bp = (wq * 64 + lane) * 20;
      o10 += *(const f32x4*)&Obuf[bp + 0];
      o11 += *(const f32x4*)&Obuf[bp + 4];
      o12 += *(const f32x4*)&Obuf[bp + 8];
      o13 += *(const f32x4*)&Obuf[bp + 12];
      ls1 += lbufF[wq * 64 + lane];
    }
  }

  // Finalize: wave 0 writes q-set 0, wave 1 writes q-set 1.
  if (w == 0) {
    float L = ls0;
    L += __shfl_xor(L, 16);
    L += __shfl_xor(L, 32);
#pragma unroll
    for (int r = 0; r < 4; ++r) {
      const float inv = 1.f / __shfl(L, quad * 4 + r);
      const int row = q0 + quad * 4 + r;
      u16* cp = ctx + (size_t)row * DIM + h * 64 + l16;
      cp[0]  = f2bf(o00[r] * inv);
      cp[16] = f2bf(o01[r] * inv);
      cp[32] = f2bf(o02[r] * inv);
      cp[48] = f2bf(o03[r] * inv);
    }
  } else if (w == 1) {
    float L = ls1;
    L += __shfl_xor(L, 16);
    L += __shfl_xor(L, 32);
#pragma unroll
    for (int r = 0; r < 4; ++r) {
      const float inv = 1.f / __shfl(L, quad * 4 + r);
      const int row = q0 + 16 + quad * 4 + r;
      u16* cp = ctx + (size_t)row * DIM + h * 64 + l16;
      cp[0]  = f2bf(o10[r] * inv);
      cp[16] = f2bf(o11[r] * inv);
      cp[32] = f2bf(o12[r] * inv);
      cp[48] = f2bf(o13[r] * inv);
    }
  }
}

// ---------------------------------------------------------------------------
extern "C" void kernel_launch(void* const* d_in, const int* in_sizes, int n_in,
                              void* d_out, int out_size, void* d_ws,
                              size_t ws_size, hipStream_t stream) {
  const float* x  = (const float*)d_in[0];
  const float* wq = (const float*)d_in[1];
  const float* wk = (const float*)d_in[2];
  const float* wv = (const float*)d_in[3];
  const float* wo = (const float*)d_in[4];
  const float* bo = (const float*)d_in[5];

  const size_t n_x = (size_t)S_LEN * DIM;
  const size_t n_w = (size_t)DIM * DIM;
  u16* xb  = (u16*)d_ws;
  u16* wtq = xb + n_x;
  u16* wtk = wtq + n_w;
  u16* wtv = wtk + n_w;
  u16* wto = wtv + n_w;
  u16* Qb  = wto + n_w;
  u16* Kb  = Qb + n_x;
  u16* VTb = Kb + n_x;   // [768][4096]
  u16* ctx = VTb + n_x;

  prep_kernel<<<dim3(12, 12, 5), 256, 0, stream>>>(
      x, wq, wk, wv, wo, xb, wtq, wtk, wtv, wto);

  // Fused QKV: N = 3*768, 128x96 tiles -> 24x32 = 768 blocks, dbuf 56KB.
  mfma_gemm_kernel<0><<<dim3(24, 32), 256, 0, stream>>>(
      xb, wtq, wtk, wtv, nullptr, Qb, Kb, VTb, nullptr);

  // Attention: 1536 single-tile blocks, 32KB LDS, 4 blocks/CU (VGPR cap).
  attn_mfma_kernel<<<dim3(1536), 256, 0, stream>>>(Qb, Kb, VTb, ctx);

  // Output GEMM: 64x96 tiles -> 8x64 = 512 blocks, dbuf 40KB, fp32 + bias.
  mfma_gemm_kernel<1><<<dim3(8, 64), 256, 0, stream>>>(
      ctx, wto, nullptr, nullptr, bo, nullptr, nullptr, nullptr, (float*)d_out);
}

// Round 12
// 159.189 us; speedup vs baseline: 1.0327x; 1.0327x over previous
//
#include <hip/hip_runtime.h>

// MultiHeadAttention: B=1, S=4096, D=768, H=12, HD=64, causal, fp32 in/out.
// Round 23: revert R22 GEMM dbuf (regressed: MODE0 2/CU residency + 1.5-round
// tail). Apply the session's one proven lever - TLP via more, smaller
// blocks - to the GEMMs, single-buffered:
//   MODE0 (QKV): BM 128->64 (MT=2), grid 24x64=1536, LDS 20KB -> 6 blk/CU
//   MODE1 (out): BM 64->32 (MT=1),  grid 8x128=1024, LDS 16KB -> 4 blk/CU
// Staged bytes rise 1.4x (all L2-resident; LDS-write budget ~5us aggregate)
// in exchange for 2x latency cover on the per-K-step vmcnt(0) drain.
// Attn reverts to the EXACT R16 kernel (best measured: 47.6us, e2e 154.5):
// 1536 blocks, qw/kw wave split, 32KB LDS, 5 blocks/CU, 3-barrier phase,
// fixed-max softmax, in-register P (swapped QK^T + cvt_pk + permlane).
// Prep unchanged.

typedef short bf16x8 __attribute__((ext_vector_type(8)));
typedef float f32x4 __attribute__((ext_vector_type(4)));
typedef unsigned short u16;

static constexpr int S_LEN = 4096;
static constexpr int DIM   = 768;
static constexpr int NH    = 12;
// softmax scale folded into Q projection: 1/sqrt(64) * log2(e)
static constexpr float QSCALE = 0.125f * 1.44269504088896340736f;

__device__ inline u16 f2bf(float f) {
  union { float f; unsigned int u; } v; v.f = f;
  unsigned int r = v.u + 0x7FFFu + ((v.u >> 16) & 1u);  // RNE
  return (u16)(r >> 16);
}

__device__ inline void gload_lds16(const u16* g, u16* s) {
  __builtin_amdgcn_global_load_lds(
      (const __attribute__((address_space(1))) unsigned int*)g,
      (__attribute__((address_space(3))) unsigned int*)s, 16, 0, 0);
}

// ---------------------------------------------------------------------------
// Prep: z<4 -> transpose W[z] fp32 -> bf16 W^T; z==4 -> convert x -> bf16.
__global__ __launch_bounds__(256)
void prep_kernel(const float* __restrict__ x, const float* __restrict__ w0,
                 const float* __restrict__ w1, const float* __restrict__ w2,
                 const float* __restrict__ w3, u16* __restrict__ xb,
                 u16* __restrict__ t0, u16* __restrict__ t1,
                 u16* __restrict__ t2, u16* __restrict__ t3) {
  if (blockIdx.z == 4) {
    const size_t n = (size_t)S_LEN * DIM;
    const int id = blockIdx.y * 12 + blockIdx.x;
    const size_t stride = (size_t)144 * 256 * 8;
    for (size_t i = ((size_t)id * 256 + threadIdx.x) * 8; i < n; i += stride) {
      const float4 a = *(const float4*)(x + i);
      const float4 b = *(const float4*)(x + i + 4);
      bf16x8 o;
      o[0] = (short)f2bf(a.x); o[1] = (short)f2bf(a.y);
      o[2] = (short)f2bf(a.z); o[3] = (short)f2bf(a.w);
      o[4] = (short)f2bf(b.x); o[5] = (short)f2bf(b.y);
      o[6] = (short)f2bf(b.z); o[7] = (short)f2bf(b.w);
      *(bf16x8*)(xb + i) = o;
    }
    return;
  }
  __shared__ float T[64][65];
  const float* src; u16* dst;
  switch (blockIdx.z) {
    case 0: src = w0; dst = t0; break;
    case 1: src = w1; dst = t1; break;
    case 2: src = w2; dst = t2; break;
    default: src = w3; dst = t3; break;
  }
  const int k0 = blockIdx.y * 64, n0 = blockIdx.x * 64;
  const int r = threadIdx.x >> 2, c0 = (threadIdx.x & 3) * 16;
#pragma unroll
  for (int i = 0; i < 4; ++i) {
    const float4 v = *(const float4*)(src + (size_t)(k0 + r) * DIM + n0 + c0 + i * 4);
    T[r][c0 + i * 4 + 0] = v.x;
    T[r][c0 + i * 4 + 1] = v.y;
    T[r][c0 + i * 4 + 2] = v.z;
    T[r][c0 + i * 4 + 3] = v.w;
  }
  __syncthreads();
  bf16x8 o0, o1;
#pragma unroll
  for (int i = 0; i < 8; ++i) {
    o0[i] = (short)f2bf(T[c0 + i][r]);
    o1[i] = (short)f2bf(T[c0 + 8 + i][r]);
  }
  *(bf16x8*)(dst + (size_t)(n0 + r) * DIM + k0 + c0) = o0;
  *(bf16x8*)(dst + (size_t)(n0 + r) * DIM + k0 + c0 + 8) = o1;
}

// ---------------------------------------------------------------------------
// MFMA GEMM, BK=64, BN=96, single-buffered global_load_lds staging with XOR
// chunk swizzle (2-barrier loop).
// MODE 0: fused QKV (BM=64, grid 24x64, 6 blk/CU). wi = n0/768: Q (scaled),
//         K row-major bf16 via SWAPPED mfma (C^T frag -> packed 8B stores);
//         V -> VT[768][4096] via normal orientation (already packed).
// MODE 1: out GEMM (BM=32, grid 8x128, 4 blk/CU), fp32 + bias, swapped ->
//         float4 stores.
template <int MODE>
__global__ __launch_bounds__(256)
void mfma_gemm_kernel(const u16* __restrict__ A, const u16* __restrict__ Bq,
                      const u16* __restrict__ Bk, const u16* __restrict__ Bv,
                      const float* __restrict__ bias, u16* __restrict__ Qb,
                      u16* __restrict__ Kb, u16* __restrict__ VT,
                      float* __restrict__ Out) {
  constexpr int MT = (MODE == 0) ? 2 : 1;   // m-frags (16) per wave
  constexpr int BM = MT * 32;
  __shared__ __align__(16) u16 Al[BM * 64];
  __shared__ __align__(16) u16 Bl[96 * 64];

  const int tid  = threadIdx.x;
  const int wv   = tid >> 6;
  const int lane = tid & 63;
  const int quad = lane >> 4;
  const int l16  = lane & 15;
  const int wr = wv >> 1, wc = wv & 1;
  const int m0 = blockIdx.y * BM;
  const int n0 = blockIdx.x * 96;

  int wi = 0, nb = n0;
  const u16* BT = Bq;
  if (MODE == 0) {
    wi = n0 / DIM;
    nb = n0 - wi * DIM;
    BT = (wi == 0) ? Bq : (wi == 1) ? Bk : Bv;
  }

  const int sr8 = lane >> 3;              // row within 8-row staging slab
  const int sc  = ((lane & 7) ^ sr8) * 8; // swizzled source chunk (u16)
  const int key = l16 & 7;                // read-side swizzle key

  const bool swp = (MODE == 1) || (wi < 2);  // uniform per block

  f32x4 acc[MT][3] = {};

  for (int k0 = 0; k0 < DIM; k0 += 64) {
    __syncthreads();
#pragma unroll
    for (int j = 0; j < MT; ++j)
      gload_lds16(A + (size_t)(m0 + wv * (BM / 4) + j * 8 + sr8) * DIM + k0 + sc,
                  &Al[(wv * (BM / 4) + j * 8) * 64]);
#pragma unroll
    for (int j = 0; j < 3; ++j)
      gload_lds16(BT + (size_t)(nb + wv * 24 + j * 8 + sr8) * DIM + k0 + sc,
                  &Bl[(wv * 24 + j * 8) * 64]);
    __syncthreads();

#pragma unroll
    for (int kh = 0; kh < 2; ++kh) {
      const int cb = kh * 4;
      bf16x8 af[MT], bfr[3];
#pragma unroll
      for (int mt = 0; mt < MT; ++mt) {
        const int row = wr * (BM / 2) + mt * 16 + l16;
        af[mt] = *(const bf16x8*)&Al[row * 64 + ((cb + quad) ^ key) * 8];
      }
#pragma unroll
      for (int nt = 0; nt < 3; ++nt) {
        const int row = wc * 48 + nt * 16 + l16;
        bfr[nt] = *(const bf16x8*)&Bl[row * 64 + ((cb + quad) ^ key) * 8];
      }
      if (swp) {
        // C^T: D = Bfrag x Afrag -> lane holds row m=l16, cols n=quad*4+r.
#pragma unroll
        for (int mt = 0; mt < MT; ++mt)
#pragma unroll
          for (int nt = 0; nt < 3; ++nt)
            acc[mt][nt] = __builtin_amdgcn_mfma_f32_16x16x32_bf16(
                bfr[nt], af[mt], acc[mt][nt], 0, 0, 0);
      } else {
#pragma unroll
        for (int mt = 0; mt < MT; ++mt)
#pragma unroll
          for (int nt = 0; nt < 3; ++nt)
            acc[mt][nt] = __builtin_amdgcn_mfma_f32_16x16x32_bf16(
                af[mt], bfr[nt], acc[mt][nt], 0, 0, 0);
      }
    }
  }

  if (MODE == 0 && wi >= 2) {
    // V path (normal orientation): lane holds col=l16, rows quad*4+r.
#pragma unroll
    for (int mt = 0; mt < MT; ++mt) {
#pragma unroll
      for (int nt = 0; nt < 3; ++nt) {
        const int row  = m0 + wr * (BM / 2) + mt * 16 + quad * 4;
        const int ncol = nb + wc * 48 + nt * 16 + l16;
        u16 pk[4];
#pragma unroll
        for (int r = 0; r < 4; ++r) pk[r] = f2bf(acc[mt][nt][r]);
        unsigned long long v;
        __builtin_memcpy(&v, pk, 8);
        *(unsigned long long*)(VT + (size_t)ncol * S_LEN + row) = v;
      }
    }
  } else if (MODE == 0) {
    // Q/K path (swapped): packed 8B row-major stores.
    u16* dst = (wi == 0) ? Qb : Kb;
    const float sc_out = (wi == 0) ? QSCALE : 1.0f;
#pragma unroll
    for (int mt = 0; mt < MT; ++mt) {
#pragma unroll
      for (int nt = 0; nt < 3; ++nt) {
        const int row = m0 + wr * (BM / 2) + mt * 16 + l16;
        const int ncb = nb + wc * 48 + nt * 16 + quad * 4;
        u16 pk[4];
#pragma unroll
        for (int r = 0; r < 4; ++r) pk[r] = f2bf(acc[mt][nt][r] * sc_out);
        unsigned long long v;
        __builtin_memcpy(&v, pk, 8);
        *(unsigned long long*)(dst + (size_t)row * DIM + ncb) = v;
      }
    }
  } else {
    // Out GEMM (swapped): float4 stores + float4 bias loads.
#pragma unroll
    for (int mt = 0; mt < MT; ++mt) {
#pragma unroll
      for (int nt = 0; nt < 3; ++nt) {
        const int row = m0 + wr * (BM / 2) + mt * 16 + l16;
        const int ncb = n0 + wc * 48 + nt * 16 + quad * 4;
        const float4 b4 = *(const float4*)(bias + ncb);
        float4 ov;
        ov.x = acc[mt][nt][0] + b4.x;
        ov.y = acc[mt][nt][1] + b4.y;
        ov.z = acc[mt][nt][2] + b4.z;
        ov.w = acc[mt][nt][3] + b4.w;
        *(float4*)(Out + (size_t)row * DIM + ncb) = ov;
      }
    }
  }
}

// ---------------------------------------------------------------------------
// Flash causal attention (EXACT R16 kernel - best measured). 1536 blocks x
// 256 thr, one 32-row q-tile each. Wave w: q-subtile qw=w>>1, kv-half
// kw=w&1. 128-wide kv slabs, K and V single-buffered (32KB LDS -> 5
// blocks/CU). Per-phase: stage K,V; B vmcnt(4) (K in); QK^T+softmax; C
// vmcnt(0) (V in); PV. In-register P via swapped QK^T + cvt_pk + permlane.
// kw-halves combine via stride-20 Obuf.
__global__ __launch_bounds__(256, 5)
void attn_mfma_kernel(const u16* __restrict__ Qb, const u16* __restrict__ Kb,
                      const u16* __restrict__ VTb, u16* __restrict__ ctx) {
  // Kl (128x64) + Vl (64x128) = 16384 u16 = 32 KB exact. Obuf reuses front.
  __shared__ __align__(16) u16 KVl[128 * 64 + 64 * 128];
  u16* const Kl = KVl;                   // [kv][d] swizzled
  u16* const Vl = KVl + 128 * 64;        // [d][kv] swizzled

  const int tid  = threadIdx.x;
  const int w    = tid >> 6;
  const int lane = tid & 63;
  const int quad = lane >> 4;
  const int l16  = lane & 15;
  const int qw   = w >> 1;
  const int kw   = w & 1;
  const int key  = l16 & 7;

  // Mapping: big tiles dispatch first (LPT); h = id%12 keeps per-XCD head
  // set = {x, x+4, x+8} mod 12 (3 heads x ~2MB K+V, L2-resident per XCD).
  const int id = blockIdx.x;
  const int to = id / 12;
  const int h  = id - to * 12;
  const int qt = 127 - to;
  const int q0 = qt * 32;

  const int sr8  = lane >> 3;               // K: row-in-slab
  const int scK  = ((lane & 7) ^ sr8) * 8;  // K: swizzled source col
  const int sr16 = lane >> 4;               // V: row-in-slab

  // Q fragments in registers (Qb is L2-hot; no LDS round-trip).
  const u16* qptr = Qb + (size_t)(q0 + qw * 16 + l16) * DIM + h * 64 + quad * 8;
  const bf16x8 aq0 = *(const bf16x8*)(qptr);
  const bf16x8 aq1 = *(const bf16x8*)(qptr + 32);

  f32x4 o[4] = {};
  float l_s = 0.f;
  const int qg = q0 + qw * 16 + l16;   // lane-fixed q row (swapped layout)

  const int nkt = qt / 2 + 1;          // 64-wide k-tiles
  const int niter = (nkt + 1) >> 1;    // 128-wide slabs
  const int my_last = nkt - 1;         // diagonal tile index

#pragma unroll 1
  for (int i = 0; i < niter; ++i) {
    const int k0g = i * 128;
    // Barrier A: all LDS reads of slab i-1 retired before Kl/Vl overwrite.
    asm volatile("s_waitcnt lgkmcnt(0)" ::: "memory");
    __builtin_amdgcn_s_barrier();

    // Stage K(i) then V(i) (issue order matters for counted vmcnt).
#pragma unroll
    for (int j = 0; j < 4; ++j)
      gload_lds16(Kb + (size_t)(k0g + w * 32 + j * 8 + sr8) * DIM + h * 64 + scK,
                  &Kl[(w * 32 + j * 8) * 64]);
#pragma unroll
    for (int j = 0; j < 4; ++j) {
      const int vrow = w * 16 + j * 4 + sr16;
      const int vcol = ((lane & 15) ^ (vrow & 7)) * 8;
      gload_lds16(VTb + (size_t)(h * 64 + vrow) * S_LEN + k0g + vcol,
                  &Vl[(w * 16 + j * 4) * 128]);
    }
    // Barrier B: K(i) landed (V(i)'s 4 loads stay in flight). K latency is
    // hidden by the other ~4 blocks/CU worth of waves (TLP).
    asm volatile("s_waitcnt vmcnt(4)" ::: "memory");
    __builtin_amdgcn_s_barrier();

    const int kt_w = 2 * i + kw;
    const bool act = kt_w < nkt;
    bf16x8 pa0, pa1;
    if (act) {
      __builtin_amdgcn_s_setprio(1);
      // S^T = K Q^T (swapped): lane holds q=l16, kv=16t+4*quad+r.
      f32x4 s[4];
#pragma unroll
      for (int t = 0; t < 4; ++t) {
        const int row = kw * 64 + t * 16 + l16;
        const bf16x8 bk0 = *(const bf16x8*)&Kl[row * 64 + (quad ^ key) * 8];
        const bf16x8 bk1 = *(const bf16x8*)&Kl[row * 64 + ((quad ^ 4) ^ key) * 8];
        s[t] = __builtin_amdgcn_mfma_f32_16x16x32_bf16(
            bk0, aq0, f32x4{0.f, 0.f, 0.f, 0.f}, 0, 0, 0);
        s[t] = __builtin_amdgcn_mfma_f32_16x16x32_bf16(bk1, aq1, s[t], 0, 0, 0);
      }

      // P = 2^S; mask on diagonal tile; pack pairs via v_cvt_pk_bf16_f32.
      unsigned Wt[4][2];
      if (kt_w == my_last) {
#pragma unroll
        for (int t = 0; t < 4; ++t) {
          float pr[4];
#pragma unroll
          for (int r = 0; r < 4; ++r) {
            const int kvg = k0g + kw * 64 + t * 16 + quad * 4 + r;
            float p = __builtin_amdgcn_exp2f(s[t][r]);
            if (kvg > qg) p = 0.f;
            l_s += p;
            pr[r] = p;
          }
          asm("v_cvt_pk_bf16_f32 %0, %1, %2" : "=v"(Wt[t][0]) : "v"(pr[0]), "v"(pr[1]));
          asm("v_cvt_pk_bf16_f32 %0, %1, %2" : "=v"(Wt[t][1]) : "v"(pr[2]), "v"(pr[3]));
        }
      } else {
#pragma unroll
        for (int t = 0; t < 4; ++t) {
          float pr[4];
#pragma unroll
          for (int r = 0; r < 4; ++r) {
            const float p = __builtin_amdgcn_exp2f(s[t][r]);
            l_s += p;
            pr[r] = p;
          }
          asm("v_cvt_pk_bf16_f32 %0, %1, %2" : "=v"(Wt[t][0]) : "v"(pr[0]), "v"(pr[1]));
          asm("v_cvt_pk_bf16_f32 %0, %1, %2" : "=v"(Wt[t][1]) : "v"(pr[2]), "v"(pr[3]));
        }
      }

      // Quad transpose in VALU: permlane32_swap then permlane16_swap per
      // register pair. Lane(b5=quad>>1,b4=quad&1) ends with kv 8*quad+{0..7}.
      {
        unsigned a0 = Wt[0][0], b0 = Wt[1][0];
        unsigned a1 = Wt[0][1], b1 = Wt[1][1];
        asm("v_permlane32_swap_b32 %0, %1" : "+v"(a0), "+v"(b0));
        asm("v_permlane16_swap_b32 %0, %1" : "+v"(a0), "+v"(b0));
        asm("v_permlane32_swap_b32 %0, %1" : "+v"(a1), "+v"(b1));
        asm("v_permlane16_swap_b32 %0, %1" : "+v"(a1), "+v"(b1));
        union { unsigned u[4]; bf16x8 v; } U0;
        U0.u[0] = a0; U0.u[1] = a1; U0.u[2] = b0; U0.u[3] = b1;
        pa0 = U0.v;
        unsigned c0 = Wt[2][0], d0 = Wt[3][0];
        unsigned c1 = Wt[2][1], d1 = Wt[3][1];
        asm("v_permlane32_swap_b32 %0, %1" : "+v"(c0), "+v"(d0));
        asm("v_permlane16_swap_b32 %0, %1" : "+v"(c0), "+v"(d0));
        asm("v_permlane32_swap_b32 %0, %1" : "+v"(c1), "+v"(d1));
        asm("v_permlane16_swap_b32 %0, %1" : "+v"(c1), "+v"(d1));
        union { unsigned u[4]; bf16x8 v; } U1;
        U1.u[0] = c0; U1.u[1] = c1; U1.u[2] = d0; U1.u[3] = d1;
        pa1 = U1.v;
      }
    }

    // Barrier C (ALL waves): V(i) landed for every wave's quarter.
    asm volatile("s_waitcnt vmcnt(0)" ::: "memory");
    __builtin_amdgcn_s_barrier();

    if (act) {
      // O += P V
#pragma unroll
      for (int t = 0; t < 4; ++t) {
        const int row = t * 16 + l16;  // d-row in Vl
        const int cc0 = (kw * 8 + quad) ^ key;
        const int cc1 = (kw * 8 + quad + 4) ^ key;
        const bf16x8 vb0 = *(const bf16x8*)&Vl[row * 128 + cc0 * 8];
        const bf16x8 vb1 = *(const bf16x8*)&Vl[row * 128 + cc1 * 8];
        o[t] = __builtin_amdgcn_mfma_f32_16x16x32_bf16(pa0, vb0, o[t], 0, 0, 0);
        o[t] = __builtin_amdgcn_mfma_f32_16x16x32_bf16(pa1, vb1, o[t], 0, 0, 0);
      }
      __builtin_amdgcn_s_setprio(0);
    }
  }

  // Combine kv-halves: waves w and w^1 hold partials for the same q-rows.
  // Obuf lane stride 20 floats (16B-aligned, conflict-free).
  __syncthreads();  // all waves done with Kl/Vl reads before Obuf reuse
  float* Obuf  = (float*)KVl;  // 256 lanes x 20 floats = 20 KB
  float* lbufF = Obuf + 5120;  // 256 floats = 1 KB
#pragma unroll
  for (int t = 0; t < 4; ++t)
    *(f32x4*)&Obuf[(w * 64 + lane) * 20 + t * 4] = o[t];
  lbufF[w * 64 + lane] = l_s;
  __syncthreads();
#pragma unroll
  for (int t = 0; t < 4; ++t) {
    const f32x4 po = *(const f32x4*)&Obuf[((w ^ 1) * 64 + lane) * 20 + t * 4];
    o[t] += po;
  }
  l_s += lbufF[(w ^ 1) * 64 + lane];

  if (kw == 0) {
    // Full row-sum for q=l16: reduce across quads (lane bits 4,5).
    float L = l_s;
    L += __shfl_xor(L, 16);
    L += __shfl_xor(L, 32);
#pragma unroll
    for (int r = 0; r < 4; ++r) {
      const float inv = 1.f / __shfl(L, quad * 4 + r);
      const int row = q0 + qw * 16 + quad * 4 + r;
#pragma unroll
      for (int t = 0; t < 4; ++t)
        ctx[(size_t)row * DIM + h * 64 + t * 16 + l16] = f2bf(o[t][r] * inv);
    }
  }
}

// ---------------------------------------------------------------------------
extern "C" void kernel_launch(void* const* d_in, const int* in_sizes, int n_in,
                              void* d_out, int out_size, void* d_ws,
                              size_t ws_size, hipStream_t stream) {
  const float* x  = (const float*)d_in[0];
  const float* wq = (const float*)d_in[1];
  const float* wk = (const float*)d_in[2];
  const float* wv = (const float*)d_in[3];
  const float* wo = (const float*)d_in[4];
  const float* bo = (const float*)d_in[5];

  const size_t n_x = (size_t)S_LEN * DIM;
  const size_t n_w = (size_t)DIM * DIM;
  u16* xb  = (u16*)d_ws;
  u16* wtq = xb + n_x;
  u16* wtk = wtq + n_w;
  u16* wtv = wtk + n_w;
  u16* wto = wtv + n_w;
  u16* Qb  = wto + n_w;
  u16* Kb  = Qb + n_x;
  u16* VTb = Kb + n_x;   // [768][4096]
  u16* ctx = VTb + n_x;

  prep_kernel<<<dim3(12, 12, 5), 256, 0, stream>>>(
      x, wq, wk, wv, wo, xb, wtq, wtk, wtv, wto);

  // Fused QKV: N = 3*768, 64x96 tiles -> 24x64 = 1536 blocks (6/CU, 20KB).
  mfma_gemm_kernel<0><<<dim3(24, 64), 256, 0, stream>>>(
      xb, wtq, wtk, wtv, nullptr, Qb, Kb, VTb, nullptr);

  // Attention: 1536 single-tile blocks, 5 blocks/CU (32KB LDS each).
  attn_mfma_kernel<<<dim3(1536), 256, 0, stream>>>(Qb, Kb, VTb, ctx);

  // Output GEMM: 32x96 tiles -> 8x128 = 1024 blocks (4/CU, 16KB), fp32+bias.
  mfma_gemm_kernel<1><<<dim3(8, 128), 256, 0, stream>>>(
      ctx, wto, nullptr, nullptr, bo, nullptr, nullptr, nullptr, (float*)d_out);
}

// Round 13
// 155.306 us; speedup vs baseline: 1.0585x; 1.0250x over previous
//
#include <hip/hip_runtime.h>

// MultiHeadAttention: B=1, S=4096, D=768, H=12, HD=64, causal, fp32 in/out.
// Round 24: exact R16 restoration - the session's best measured point
// (attn 47.6us, e2e 154.5us). Ledger: R13-15 (attn pipelining), R17/R19
// (split-K), R18 (direct-global V), R20/R21 (kv-quarter dedup), R22 (GEMM
// dbuf), R23 (GEMM small-tile TLP) all lost to or tied this configuration.
//   - prep: W transpose fp32->bf16 W^T + x->bf16 (unchanged all session)
//   - QKV GEMM: BM=128 BN=96, grid 24x32=768 (3/CU exact), single-buffered
//     2-barrier loop, XOR chunk swizzle
//   - attn: 1536 blocks, qw/kw wave split, 32KB LDS (5 blocks/CU),
//     3-barrier phase (A lgkm0 / B vmcnt4 / C vmcnt0), fixed-max softmax,
//     in-register P via swapped QK^T + cvt_pk + permlane quad transpose
//   - out GEMM: BM=64 BN=96, grid 8x64=512 (2/CU exact), fp32 + bias

typedef short bf16x8 __attribute__((ext_vector_type(8)));
typedef float f32x4 __attribute__((ext_vector_type(4)));
typedef unsigned short u16;

static constexpr int S_LEN = 4096;
static constexpr int DIM   = 768;
static constexpr int NH    = 12;
// softmax scale folded into Q projection: 1/sqrt(64) * log2(e)
static constexpr float QSCALE = 0.125f * 1.44269504088896340736f;

__device__ inline u16 f2bf(float f) {
  union { float f; unsigned int u; } v; v.f = f;
  unsigned int r = v.u + 0x7FFFu + ((v.u >> 16) & 1u);  // RNE
  return (u16)(r >> 16);
}

__device__ inline void gload_lds16(const u16* g, u16* s) {
  __builtin_amdgcn_global_load_lds(
      (const __attribute__((address_space(1))) unsigned int*)g,
      (__attribute__((address_space(3))) unsigned int*)s, 16, 0, 0);
}

// ---------------------------------------------------------------------------
// Prep: z<4 -> transpose W[z] fp32 -> bf16 W^T; z==4 -> convert x -> bf16.
__global__ __launch_bounds__(256)
void prep_kernel(const float* __restrict__ x, const float* __restrict__ w0,
                 const float* __restrict__ w1, const float* __restrict__ w2,
                 const float* __restrict__ w3, u16* __restrict__ xb,
                 u16* __restrict__ t0, u16* __restrict__ t1,
                 u16* __restrict__ t2, u16* __restrict__ t3) {
  if (blockIdx.z == 4) {
    const size_t n = (size_t)S_LEN * DIM;
    const int id = blockIdx.y * 12 + blockIdx.x;
    const size_t stride = (size_t)144 * 256 * 8;
    for (size_t i = ((size_t)id * 256 + threadIdx.x) * 8; i < n; i += stride) {
      const float4 a = *(const float4*)(x + i);
      const float4 b = *(const float4*)(x + i + 4);
      bf16x8 o;
      o[0] = (short)f2bf(a.x); o[1] = (short)f2bf(a.y);
      o[2] = (short)f2bf(a.z); o[3] = (short)f2bf(a.w);
      o[4] = (short)f2bf(b.x); o[5] = (short)f2bf(b.y);
      o[6] = (short)f2bf(b.z); o[7] = (short)f2bf(b.w);
      *(bf16x8*)(xb + i) = o;
    }
    return;
  }
  __shared__ float T[64][65];
  const float* src; u16* dst;
  switch (blockIdx.z) {
    case 0: src = w0; dst = t0; break;
    case 1: src = w1; dst = t1; break;
    case 2: src = w2; dst = t2; break;
    default: src = w3; dst = t3; break;
  }
  const int k0 = blockIdx.y * 64, n0 = blockIdx.x * 64;
  const int r = threadIdx.x >> 2, c0 = (threadIdx.x & 3) * 16;
#pragma unroll
  for (int i = 0; i < 4; ++i) {
    const float4 v = *(const float4*)(src + (size_t)(k0 + r) * DIM + n0 + c0 + i * 4);
    T[r][c0 + i * 4 + 0] = v.x;
    T[r][c0 + i * 4 + 1] = v.y;
    T[r][c0 + i * 4 + 2] = v.z;
    T[r][c0 + i * 4 + 3] = v.w;
  }
  __syncthreads();
  bf16x8 o0, o1;
#pragma unroll
  for (int i = 0; i < 8; ++i) {
    o0[i] = (short)f2bf(T[c0 + i][r]);
    o1[i] = (short)f2bf(T[c0 + 8 + i][r]);
  }
  *(bf16x8*)(dst + (size_t)(n0 + r) * DIM + k0 + c0) = o0;
  *(bf16x8*)(dst + (size_t)(n0 + r) * DIM + k0 + c0 + 8) = o1;
}

// ---------------------------------------------------------------------------
// MFMA GEMM, BK=64, BN=96, global_load_lds staging with XOR chunk swizzle.
// MODE 0: fused QKV (BM=128, grid 24x32). wi = n0/768: Q (scaled), K
//         row-major bf16 via SWAPPED mfma (C^T frag -> packed 8B stores);
//         V -> VT[768][4096] via normal orientation (already packed).
// MODE 1: out GEMM (BM=64, grid 8x64), fp32 + bias, swapped -> float4 stores.
template <int MODE>
__global__ __launch_bounds__(256)
void mfma_gemm_kernel(const u16* __restrict__ A, const u16* __restrict__ Bq,
                      const u16* __restrict__ Bk, const u16* __restrict__ Bv,
                      const float* __restrict__ bias, u16* __restrict__ Qb,
                      u16* __restrict__ Kb, u16* __restrict__ VT,
                      float* __restrict__ Out) {
  constexpr int MT = (MODE == 0) ? 4 : 2;   // m-frags (16) per wave
  constexpr int BM = MT * 32;
  __shared__ __align__(16) u16 Al[BM * 64];
  __shared__ __align__(16) u16 Bl[96 * 64];

  const int tid  = threadIdx.x;
  const int wv   = tid >> 6;
  const int lane = tid & 63;
  const int quad = lane >> 4;
  const int l16  = lane & 15;
  const int wr = wv >> 1, wc = wv & 1;
  const int m0 = blockIdx.y * BM;
  const int n0 = blockIdx.x * 96;

  int wi = 0, nb = n0;
  const u16* BT = Bq;
  if (MODE == 0) {
    wi = n0 / DIM;
    nb = n0 - wi * DIM;
    BT = (wi == 0) ? Bq : (wi == 1) ? Bk : Bv;
  }

  const int sr8 = lane >> 3;              // row within 8-row staging slab
  const int sc  = ((lane & 7) ^ sr8) * 8; // swizzled source chunk (u16)
  const int key = l16 & 7;                // read-side swizzle key

  const bool swp = (MODE == 1) || (wi < 2);  // uniform per block

  f32x4 acc[MT][3] = {};

  for (int k0 = 0; k0 < DIM; k0 += 64) {
    __syncthreads();
#pragma unroll
    for (int j = 0; j < MT; ++j)
      gload_lds16(A + (size_t)(m0 + wv * (BM / 4) + j * 8 + sr8) * DIM + k0 + sc,
                  &Al[(wv * (BM / 4) + j * 8) * 64]);
#pragma unroll
    for (int j = 0; j < 3; ++j)
      gload_lds16(BT + (size_t)(nb + wv * 24 + j * 8 + sr8) * DIM + k0 + sc,
                  &Bl[(wv * 24 + j * 8) * 64]);
    __syncthreads();

#pragma unroll
    for (int kh = 0; kh < 2; ++kh) {
      const int cb = kh * 4;
      bf16x8 af[MT], bfr[3];
#pragma unroll
      for (int mt = 0; mt < MT; ++mt) {
        const int row = wr * (BM / 2) + mt * 16 + l16;
        af[mt] = *(const bf16x8*)&Al[row * 64 + ((cb + quad) ^ key) * 8];
      }
#pragma unroll
      for (int nt = 0; nt < 3; ++nt) {
        const int row = wc * 48 + nt * 16 + l16;
        bfr[nt] = *(const bf16x8*)&Bl[row * 64 + ((cb + quad) ^ key) * 8];
      }
      if (swp) {
        // C^T: D = Bfrag x Afrag -> lane holds row m=l16, cols n=quad*4+r.
#pragma unroll
        for (int mt = 0; mt < MT; ++mt)
#pragma unroll
          for (int nt = 0; nt < 3; ++nt)
            acc[mt][nt] = __builtin_amdgcn_mfma_f32_16x16x32_bf16(
                bfr[nt], af[mt], acc[mt][nt], 0, 0, 0);
      } else {
#pragma unroll
        for (int mt = 0; mt < MT; ++mt)
#pragma unroll
          for (int nt = 0; nt < 3; ++nt)
            acc[mt][nt] = __builtin_amdgcn_mfma_f32_16x16x32_bf16(
                af[mt], bfr[nt], acc[mt][nt], 0, 0, 0);
      }
    }
  }

  if (MODE == 0 && wi >= 2) {
    // V path (normal orientation): lane holds col=l16, rows quad*4+r.
#pragma unroll
    for (int mt = 0; mt < MT; ++mt) {
#pragma unroll
      for (int nt = 0; nt < 3; ++nt) {
        const int row  = m0 + wr * (BM / 2) + mt * 16 + quad * 4;
        const int ncol = nb + wc * 48 + nt * 16 + l16;
        u16 pk[4];
#pragma unroll
        for (int r = 0; r < 4; ++r) pk[r] = f2bf(acc[mt][nt][r]);
        unsigned long long v;
        __builtin_memcpy(&v, pk, 8);
        *(unsigned long long*)(VT + (size_t)ncol * S_LEN + row) = v;
      }
    }
  } else if (MODE == 0) {
    // Q/K path (swapped): packed 8B row-major stores.
    u16* dst = (wi == 0) ? Qb : Kb;
    const float sc_out = (wi == 0) ? QSCALE : 1.0f;
#pragma unroll
    for (int mt = 0; mt < MT; ++mt) {
#pragma unroll
      for (int nt = 0; nt < 3; ++nt) {
        const int row = m0 + wr * (BM / 2) + mt * 16 + l16;
        const int ncb = nb + wc * 48 + nt * 16 + quad * 4;
        u16 pk[4];
#pragma unroll
        for (int r = 0; r < 4; ++r) pk[r] = f2bf(acc[mt][nt][r] * sc_out);
        unsigned long long v;
        __builtin_memcpy(&v, pk, 8);
        *(unsigned long long*)(dst + (size_t)row * DIM + ncb) = v;
      }
    }
  } else {
    // Out GEMM (swapped): float4 stores + float4 bias loads.
#pragma unroll
    for (int mt = 0; mt < MT; ++mt) {
#pragma unroll
      for (int nt = 0; nt < 3; ++nt) {
        const int row = m0 + wr * (BM / 2) + mt * 16 + l16;
        const int ncb = n0 + wc * 48 + nt * 16 + quad * 4;
        const float4 b4 = *(const float4*)(bias + ncb);
        float4 ov;
        ov.x = acc[mt][nt][0] + b4.x;
        ov.y = acc[mt][nt][1] + b4.y;
        ov.z = acc[mt][nt][2] + b4.z;
        ov.w = acc[mt][nt][3] + b4.w;
        *(float4*)(Out + (size_t)row * DIM + ncb) = ov;
      }
    }
  }
}

// ---------------------------------------------------------------------------
// Flash causal attention (exact R16). 1536 blocks x 256 thr, one 32-row
// q-tile each. Wave w: q-subtile qw=w>>1, kv-half kw=w&1. 128-wide kv
// slabs, K and V single-buffered (32KB LDS -> 5 blocks/CU). Per-phase:
// stage K,V; B vmcnt(4) (K in); QK^T+softmax; C vmcnt(0) (V in); PV.
// In-register P via swapped QK^T + cvt_pk + permlane. kw-halves combine
// via stride-20 Obuf.
__global__ __launch_bounds__(256, 5)
void attn_mfma_kernel(const u16* __restrict__ Qb, const u16* __restrict__ Kb,
                      const u16* __restrict__ VTb, u16* __restrict__ ctx) {
  // Kl (128x64) + Vl (64x128) = 16384 u16 = 32 KB exact. Obuf reuses front.
  __shared__ __align__(16) u16 KVl[128 * 64 + 64 * 128];
  u16* const Kl = KVl;                   // [kv][d] swizzled
  u16* const Vl = KVl + 128 * 64;        // [d][kv] swizzled

  const int tid  = threadIdx.x;
  const int w    = tid >> 6;
  const int lane = tid & 63;
  const int quad = lane >> 4;
  const int l16  = lane & 15;
  const int qw   = w >> 1;
  const int kw   = w & 1;
  const int key  = l16 & 7;

  // Mapping: big tiles dispatch first (LPT); h = id%12 keeps per-XCD head
  // set = {x, x+4, x+8} mod 12 (3 heads x ~2MB K+V, L2-resident per XCD).
  const int id = blockIdx.x;
  const int to = id / 12;
  const int h  = id - to * 12;
  const int qt = 127 - to;
  const int q0 = qt * 32;

  const int sr8  = lane >> 3;               // K: row-in-slab
  const int scK  = ((lane & 7) ^ sr8) * 8;  // K: swizzled source col
  const int sr16 = lane >> 4;               // V: row-in-slab

  // Q fragments in registers (Qb is L2-hot; no LDS round-trip).
  const u16* qptr = Qb + (size_t)(q0 + qw * 16 + l16) * DIM + h * 64 + quad * 8;
  const bf16x8 aq0 = *(const bf16x8*)(qptr);
  const bf16x8 aq1 = *(const bf16x8*)(qptr + 32);

  f32x4 o[4] = {};
  float l_s = 0.f;
  const int qg = q0 + qw * 16 + l16;   // lane-fixed q row (swapped layout)

  const int nkt = qt / 2 + 1;          // 64-wide k-tiles
  const int niter = (nkt + 1) >> 1;    // 128-wide slabs
  const int my_last = nkt - 1;         // diagonal tile index

#pragma unroll 1
  for (int i = 0; i < niter; ++i) {
    const int k0g = i * 128;
    // Barrier A: all LDS reads of slab i-1 retired before Kl/Vl overwrite.
    asm volatile("s_waitcnt lgkmcnt(0)" ::: "memory");
    __builtin_amdgcn_s_barrier();

    // Stage K(i) then V(i) (issue order matters for counted vmcnt).
#pragma unroll
    for (int j = 0; j < 4; ++j)
      gload_lds16(Kb + (size_t)(k0g + w * 32 + j * 8 + sr8) * DIM + h * 64 + scK,
                  &Kl[(w * 32 + j * 8) * 64]);
#pragma unroll
    for (int j = 0; j < 4; ++j) {
      const int vrow = w * 16 + j * 4 + sr16;
      const int vcol = ((lane & 15) ^ (vrow & 7)) * 8;
      gload_lds16(VTb + (size_t)(h * 64 + vrow) * S_LEN + k0g + vcol,
                  &Vl[(w * 16 + j * 4) * 128]);
    }
    // Barrier B: K(i) landed (V(i)'s 4 loads stay in flight). K latency is
    // hidden by the other ~4 blocks/CU worth of waves (TLP).
    asm volatile("s_waitcnt vmcnt(4)" ::: "memory");
    __builtin_amdgcn_s_barrier();

    const int kt_w = 2 * i + kw;
    const bool act = kt_w < nkt;
    bf16x8 pa0, pa1;
    if (act) {
      __builtin_amdgcn_s_setprio(1);
      // S^T = K Q^T (swapped): lane holds q=l16, kv=16t+4*quad+r.
      f32x4 s[4];
#pragma unroll
      for (int t = 0; t < 4; ++t) {
        const int row = kw * 64 + t * 16 + l16;
        const bf16x8 bk0 = *(const bf16x8*)&Kl[row * 64 + (quad ^ key) * 8];
        const bf16x8 bk1 = *(const bf16x8*)&Kl[row * 64 + ((quad ^ 4) ^ key) * 8];
        s[t] = __builtin_amdgcn_mfma_f32_16x16x32_bf16(
            bk0, aq0, f32x4{0.f, 0.f, 0.f, 0.f}, 0, 0, 0);
        s[t] = __builtin_amdgcn_mfma_f32_16x16x32_bf16(bk1, aq1, s[t], 0, 0, 0);
      }

      // P = 2^S; mask on diagonal tile; pack pairs via v_cvt_pk_bf16_f32.
      unsigned Wt[4][2];
      if (kt_w == my_last) {
#pragma unroll
        for (int t = 0; t < 4; ++t) {
          float pr[4];
#pragma unroll
          for (int r = 0; r < 4; ++r) {
            const int kvg = k0g + kw * 64 + t * 16 + quad * 4 + r;
            float p = __builtin_amdgcn_exp2f(s[t][r]);
            if (kvg > qg) p = 0.f;
            l_s += p;
            pr[r] = p;
          }
          asm("v_cvt_pk_bf16_f32 %0, %1, %2" : "=v"(Wt[t][0]) : "v"(pr[0]), "v"(pr[1]));
          asm("v_cvt_pk_bf16_f32 %0, %1, %2" : "=v"(Wt[t][1]) : "v"(pr[2]), "v"(pr[3]));
        }
      } else {
#pragma unroll
        for (int t = 0; t < 4; ++t) {
          float pr[4];
#pragma unroll
          for (int r = 0; r < 4; ++r) {
            const float p = __builtin_amdgcn_exp2f(s[t][r]);
            l_s += p;
            pr[r] = p;
          }
          asm("v_cvt_pk_bf16_f32 %0, %1, %2" : "=v"(Wt[t][0]) : "v"(pr[0]), "v"(pr[1]));
          asm("v_cvt_pk_bf16_f32 %0, %1, %2" : "=v"(Wt[t][1]) : "v"(pr[2]), "v"(pr[3]));
        }
      }

      // Quad transpose in VALU: permlane32_swap then permlane16_swap per
      // register pair. Lane(b5=quad>>1,b4=quad&1) ends with kv 8*quad+{0..7}.
      {
        unsigned a0 = Wt[0][0], b0 = Wt[1][0];
        unsigned a1 = Wt[0][1], b1 = Wt[1][1];
        asm("v_permlane32_swap_b32 %0, %1" : "+v"(a0), "+v"(b0));
        asm("v_permlane16_swap_b32 %0, %1" : "+v"(a0), "+v"(b0));
        asm("v_permlane32_swap_b32 %0, %1" : "+v"(a1), "+v"(b1));
        asm("v_permlane16_swap_b32 %0, %1" : "+v"(a1), "+v"(b1));
        union { unsigned u[4]; bf16x8 v; } U0;
        U0.u[0] = a0; U0.u[1] = a1; U0.u[2] = b0; U0.u[3] = b1;
        pa0 = U0.v;
        unsigned c0 = Wt[2][0], d0 = Wt[3][0];
        unsigned c1 = Wt[2][1], d1 = Wt[3][1];
        asm("v_permlane32_swap_b32 %0, %1" : "+v"(c0), "+v"(d0));
        asm("v_permlane16_swap_b32 %0, %1" : "+v"(c0), "+v"(d0));
        asm("v_permlane32_swap_b32 %0, %1" : "+v"(c1), "+v"(d1));
        asm("v_permlane16_swap_b32 %0, %1" : "+v"(c1), "+v"(d1));
        union { unsigned u[4]; bf16x8 v; } U1;
        U1.u[0] = c0; U1.u[1] = c1; U1.u[2] = d0; U1.u[3] = d1;
        pa1 = U1.v;
      }
    }

    // Barrier C (ALL waves): V(i) landed for every wave's quarter.
    asm volatile("s_waitcnt vmcnt(0)" ::: "memory");
    __builtin_amdgcn_s_barrier();

    if (act) {
      // O += P V
#pragma unroll
      for (int t = 0; t < 4; ++t) {
        const int row = t * 16 + l16;  // d-row in Vl
        const int cc0 = (kw * 8 + quad) ^ key;
        const int cc1 = (kw * 8 + quad + 4) ^ key;
        const bf16x8 vb0 = *(const bf16x8*)&Vl[row * 128 + cc0 * 8];
        const bf16x8 vb1 = *(const bf16x8*)&Vl[row * 128 + cc1 * 8];
        o[t] = __builtin_amdgcn_mfma_f32_16x16x32_bf16(pa0, vb0, o[t], 0, 0, 0);
        o[t] = __builtin_amdgcn_mfma_f32_16x16x32_bf16(pa1, vb1, o[t], 0, 0, 0);
      }
      __builtin_amdgcn_s_setprio(0);
    }
  }

  // Combine kv-halves: waves w and w^1 hold partials for the same q-rows.
  // Obuf lane stride 20 floats (16B-aligned, conflict-free).
  __syncthreads();  // all waves done with Kl/Vl reads before Obuf reuse
  float* Obuf  = (float*)KVl;  // 256 lanes x 20 floats = 20 KB
  float* lbufF = Obuf + 5120;  // 256 floats = 1 KB
#pragma unroll
  for (int t = 0; t < 4; ++t)
    *(f32x4*)&Obuf[(w * 64 + lane) * 20 + t * 4] = o[t];
  lbufF[w * 64 + lane] = l_s;
  __syncthreads();
#pragma unroll
  for (int t = 0; t < 4; ++t) {
    const f32x4 po = *(const f32x4*)&Obuf[((w ^ 1) * 64 + lane) * 20 + t * 4];
    o[t] += po;
  }
  l_s += lbufF[(w ^ 1) * 64 + lane];

  if (kw == 0) {
    // Full row-sum for q=l16: reduce across quads (lane bits 4,5).
    float L = l_s;
    L += __shfl_xor(L, 16);
    L += __shfl_xor(L, 32);
#pragma unroll
    for (int r = 0; r < 4; ++r) {
      const float inv = 1.f / __shfl(L, quad * 4 + r);
      const int row = q0 + qw * 16 + quad * 4 + r;
#pragma unroll
      for (int t = 0; t < 4; ++t)
        ctx[(size_t)row * DIM + h * 64 + t * 16 + l16] = f2bf(o[t][r] * inv);
    }
  }
}

// ---------------------------------------------------------------------------
extern "C" void kernel_launch(void* const* d_in, const int* in_sizes, int n_in,
                              void* d_out, int out_size, void* d_ws,
                              size_t ws_size, hipStream_t stream) {
  const float* x  = (const float*)d_in[0];
  const float* wq = (const float*)d_in[1];
  const float* wk = (const float*)d_in[2];
  const float* wv = (const float*)d_in[3];
  const float* wo = (const float*)d_in[4];
  const float* bo = (const float*)d_in[5];

  const size_t n_x = (size_t)S_LEN * DIM;
  const size_t n_w = (size_t)DIM * DIM;
  u16* xb  = (u16*)d_ws;
  u16* wtq = xb + n_x;
  u16* wtk = wtq + n_w;
  u16* wtv = wtk + n_w;
  u16* wto = wtv + n_w;
  u16* Qb  = wto + n_w;
  u16* Kb  = Qb + n_x;
  u16* VTb = Kb + n_x;   // [768][4096]
  u16* ctx = VTb + n_x;

  prep_kernel<<<dim3(12, 12, 5), 256, 0, stream>>>(
      x, wq, wk, wv, wo, xb, wtq, wtk, wtv, wto);

  // Fused QKV: N = 3*768, 128x96 tiles -> 24x32 = 768 blocks (3/CU exact).
  mfma_gemm_kernel<0><<<dim3(24, 32), 256, 0, stream>>>(
      xb, wtq, wtk, wtv, nullptr, Qb, Kb, VTb, nullptr);

  // Attention: 1536 single-tile blocks, 5 blocks/CU (32KB LDS each).
  attn_mfma_kernel<<<dim3(1536), 256, 0, stream>>>(Qb, Kb, VTb, ctx);

  // Output GEMM: 64x96 tiles -> 8x64 = 512 blocks (2/CU exact), fp32 + bias.
  mfma_gemm_kernel<1><<<dim3(8, 64), 256, 0, stream>>>(
      ctx, wto, nullptr, nullptr, bo, nullptr, nullptr, nullptr, (float*)d_out);
}